// Round 1
// baseline (237.371 us; speedup 1.0000x reference)
//
#include <hip/hip_runtime.h>

#define BB 32
#define TT 256
#define SS 258
#define EE 128
#define QQ 20
#define G4 80
#define KK 50
#define LL 8
#define PAD1 2
#define PAD2 3
#define NEGV -1e30f

__device__ __forceinline__ float fexp2(float x) {
#if __has_builtin(__builtin_amdgcn_exp2f)
    return __builtin_amdgcn_exp2f(x);
#else
    return exp2f(x);
#endif
}
__device__ __forceinline__ float frcp(float x) {
#if __has_builtin(__builtin_amdgcn_rcpf)
    return __builtin_amdgcn_rcpf(x);
#else
    return 1.0f / x;
#endif
}

// log2(e), 2*log2(e)
#define L2E  1.4426950408889634f
#define L2E2 2.8853900817779268f

// ---------------------------------------------------------------------------
// Kernel 1: embedding gather + input projection for both directions.
// xproj[((dir*SS + s)*BB + b)*G4 + g] = b_dir[g] + sum_e emb[tok(s,b)][e]*W_ih_dir[e][g]
// grid = SS blocks, block = 320 threads (2 halves of 16 batch x 160 gates)
// ---------------------------------------------------------------------------
__global__ __launch_bounds__(320) void k_embed_proj(
    const int* __restrict__ x, const float* __restrict__ emb,
    const float* __restrict__ Wf, const float* __restrict__ bf,
    const float* __restrict__ Wb, const float* __restrict__ bb,
    float* __restrict__ xproj)
{
    __shared__ float xv[BB * EE];
    __shared__ int toks[BB];
    const int s = blockIdx.x, tid = threadIdx.x;
    if (tid < BB) {
        int b = tid;
        toks[b] = (s == 0) ? PAD1 : (s == SS - 1) ? PAD2 : x[b * TT + (s - 1)];
    }
    __syncthreads();
    for (int i = tid; i < BB * EE; i += 320) {
        int b = i >> 7, e = i & (EE - 1);
        xv[i] = emb[toks[b] * EE + e];
    }
    __syncthreads();

    const int g = tid % 160, half = tid / 160;
    const int dir = (g >= 80) ? 1 : 0;
    const int gg = g - dir * 80;
    const float* W = dir ? Wb : Wf;
    const float bias = dir ? bb[gg] : bf[gg];
    float acc[16];
#pragma unroll
    for (int p = 0; p < 16; ++p) acc[p] = bias;
    const float* xvb = &xv[half * 16 * EE];
    for (int e = 0; e < EE; e += 4) {
        float w0 = W[(e + 0) * G4 + gg];
        float w1 = W[(e + 1) * G4 + gg];
        float w2 = W[(e + 2) * G4 + gg];
        float w3 = W[(e + 3) * G4 + gg];
#pragma unroll
        for (int p = 0; p < 16; ++p) {
            float4 v = *(const float4*)&xvb[p * EE + e];
            acc[p] = fmaf(v.x, w0, acc[p]);
            acc[p] = fmaf(v.y, w1, acc[p]);
            acc[p] = fmaf(v.z, w2, acc[p]);
            acc[p] = fmaf(v.w, w3, acc[p]);
        }
    }
#pragma unroll
    for (int p = 0; p < 16; ++p) {
        int b = half * 16 + p;
        xproj[((dir * SS + s) * BB + b) * G4 + gg] = acc[p];
    }
}

// ---------------------------------------------------------------------------
// Kernel 2: the sequential LSTM recurrence. One wave per (dir, b): 64 blocks
// of 64 threads. Lane = gate: lanes 0..19 = i gates (and o gates as second
// accumulator), 20..39 = f, 40..59 = g(cell). h[q] lives in lane q; broadcast
// via v_readlane. Gate redistribution via ds_bpermute. xproj already has bias.
// ---------------------------------------------------------------------------
__global__ __launch_bounds__(64) void k_lstm(
    const float* __restrict__ Whf, const float* __restrict__ Whb,
    const float* __restrict__ xproj, float* __restrict__ hbuf)
{
    const int id = blockIdx.x;
    const int dir = id >> 5, b = id & 31;
    const int lane = threadIdx.x;
    const float* Wh = dir ? Whb : Whf;

    const int pg = lane;                           // primary gate col (<80, valid for all 64 lanes)
    const int sg = 60 + (lane < QQ ? lane : 0);    // secondary: o-gate col (lanes 0..19 meaningful)

    float wp[QQ], ws[QQ];
#pragma unroll
    for (int q = 0; q < QQ; ++q) {
        wp[q] = Wh[q * G4 + pg];
        ws[q] = Wh[q * G4 + sg];
    }

    const float* xpb = xproj + (size_t)(dir * SS) * BB * G4 + b * G4;
    float* hout = hbuf + (size_t)(dir * SS) * BB * QQ + b * QQ + lane;

    const bool isg = (lane >= 40) && (lane < 60);
    const float scl = isg ? -L2E2 : -L2E;
    const float mula = isg ? 2.0f : 1.0f;
    const float addb = isg ? -1.0f : 0.0f;
    const int addr20 = (lane + 20) * 4;
    const int addr40 = (lane + 40) * 4;

    float h = 0.0f, c = 0.0f;
    int sidx0 = dir ? (SS - 1) : 0;
    float xp_p = xpb[sidx0 * (BB * G4) + pg];
    float xp_s = xpb[sidx0 * (BB * G4) + sg];

    for (int s = 0; s < SS; ++s) {
        const int sn = (s + 1 < SS) ? s + 1 : s;
        const int sidxn = dir ? (SS - 1 - sn) : sn;
        // prefetch next step's input projections
        float np = xpb[sidxn * (BB * G4) + pg];
        float ns = xpb[sidxn * (BB * G4) + sg];

        float accp = xp_p, accs = xp_s;
#pragma unroll
        for (int q = 0; q < QQ; ++q) {
            float hq = __uint_as_float(__builtin_amdgcn_readlane(__float_as_uint(h), q));
            accp = fmaf(hq, wp[q], accp);
            accs = fmaf(hq, ws[q], accs);
        }
        // activation: sigmoid for i/f/o lanes, tanh (=2*sigmoid(2x)-1) for g lanes
        float tp = frcp(1.0f + fexp2(accp * scl));
        float actp = fmaf(mula, tp, addb);
        float acts = frcp(1.0f + fexp2(accs * -L2E));   // sigmoid(o) on lanes 0..19

        // redistribute to unit lanes q' = 0..19
        float sf = __uint_as_float(__builtin_amdgcn_ds_bpermute(addr20, __float_as_uint(actp)));
        float tg = __uint_as_float(__builtin_amdgcn_ds_bpermute(addr40, __float_as_uint(actp)));

        c = fmaf(sf, c, actp * tg);                      // sigma(f)*c + sigma(i)*tanh(g)
        float th = fmaf(2.0f, frcp(1.0f + fexp2(c * -L2E2)), -1.0f);  // tanh(c)
        h = acts * th;

        const int sidx = dir ? (SS - 1 - s) : s;
        if (lane < QQ) hout[(size_t)sidx * BB * QQ] = h;

        xp_p = np; xp_s = ns;
    }
}

// ---------------------------------------------------------------------------
// Kernel 3: band scores + emission assembly.
// One thread per (l, e, b); computes K=50 outputs.
// emission[l,e,b,k]; invalid (start<0) -> NEG.
// ---------------------------------------------------------------------------
__global__ __launch_bounds__(256) void k_scores(
    const float* __restrict__ hbuf,
    const float* __restrict__ W1, const float* __restrict__ b1,
    const float* __restrict__ W2, const float* __restrict__ b2,
    float* __restrict__ out)
{
    const int idx = blockIdx.x * 256 + threadIdx.x;   // == (l*TT + e)*BB + b
    const int l = idx / (TT * BB);
    const int r = idx - l * (TT * BB);
    const int e = r / BB;
    const int b = r - e * BB;
    float* op = out + (size_t)idx * KK;

    const int start = e - (LL - 1) + l;
    if (start < 0) {
#pragma unroll
        for (int k = 0; k < KK; ++k) op[k] = NEGV;
        return;
    }

    // fwd[b][t] = hf[t+1][b]; bwd[b][t] = hb[t][b]
    const float4* hfA = (const float4*)(hbuf + ((size_t)(e + 2) * BB + b) * QQ);       // fwd[b][e+1]
    const float4* hfB = (const float4*)(hbuf + ((size_t)(start + 1) * BB + b) * QQ);   // fwd[b][start]
    const float4* hbA = (const float4*)(hbuf + ((size_t)(SS + start) * BB + b) * QQ);  // bwd[b][start]
    const float4* hbB = (const float4*)(hbuf + ((size_t)(SS + e + 1) * BB + b) * QQ);  // bwd[b][e+1]

    float cat[2 * QQ];
#pragma unroll
    for (int j = 0; j < 5; ++j) {
        float4 a = hfA[j], d = hfB[j];
        cat[4 * j + 0] = a.x - d.x; cat[4 * j + 1] = a.y - d.y;
        cat[4 * j + 2] = a.z - d.z; cat[4 * j + 3] = a.w - d.w;
        float4 p = hbA[j], q = hbB[j];
        cat[QQ + 4 * j + 0] = p.x - q.x; cat[QQ + 4 * j + 1] = p.y - q.y;
        cat[QQ + 4 * j + 2] = p.z - q.z; cat[QQ + 4 * j + 3] = p.w - q.w;
    }

    float u[QQ];
#pragma unroll
    for (int j = 0; j < QQ; ++j) {
        float a = b1[j];
#pragma unroll
        for (int d = 0; d < 2 * QQ; ++d) a = fmaf(cat[d], W1[d * QQ + j], a);
        u[j] = fmaf(2.0f, frcp(1.0f + fexp2(a * -L2E2)), -1.0f);   // tanh
    }
#pragma unroll
    for (int k = 0; k < KK; ++k) {
        float a = b2[k];
#pragma unroll
        for (int j = 0; j < QQ; ++j) a = fmaf(u[j], W2[j * KK + k], a);
        op[k] = a;
    }
}

extern "C" void kernel_launch(void* const* d_in, const int* in_sizes, int n_in,
                              void* d_out, int out_size, void* d_ws, size_t ws_size,
                              hipStream_t stream)
{
    const int*   x    = (const int*)d_in[0];
    const float* emb  = (const float*)d_in[1];
    const float* Wihf = (const float*)d_in[2];
    const float* Whhf = (const float*)d_in[3];
    const float* bf   = (const float*)d_in[4];
    const float* Wihb = (const float*)d_in[5];
    const float* Whhb = (const float*)d_in[6];
    const float* bb   = (const float*)d_in[7];
    const float* W1   = (const float*)d_in[8];
    const float* b1   = (const float*)d_in[9];
    const float* W2   = (const float*)d_in[10];
    const float* b2   = (const float*)d_in[11];
    float* out = (float*)d_out;

    float* xproj = (float*)d_ws;                         // 2*258*32*80 floats
    float* hbuf  = xproj + (size_t)2 * SS * BB * G4;     // 2*258*32*20 floats

    k_embed_proj<<<SS, 320, 0, stream>>>(x, emb, Wihf, bf, Wihb, bb, xproj);
    k_lstm<<<64, 64, 0, stream>>>(Whhf, Whhb, xproj, hbuf);
    k_scores<<<(LL * TT * BB) / 256, 256, 0, stream>>>(hbuf, W1, b1, W2, b2, out);
}

// Round 2
// 233.330 us; speedup vs baseline: 1.0173x; 1.0173x over previous
//
#include <hip/hip_runtime.h>

#define BB 32
#define TT 256
#define SS 258
#define EE 128
#define QQ 20
#define G4 80
#define KK 50
#define LL 8
#define PAD1 2
#define PAD2 3
#define NEGV -1e30f

__device__ __forceinline__ float fexp2(float x) {
#if __has_builtin(__builtin_amdgcn_exp2f)
    return __builtin_amdgcn_exp2f(x);
#else
    return exp2f(x);
#endif
}
__device__ __forceinline__ float frcp(float x) {
#if __has_builtin(__builtin_amdgcn_rcpf)
    return __builtin_amdgcn_rcpf(x);
#else
    return 1.0f / x;
#endif
}

// log2(e), 2*log2(e)
#define L2E  1.4426950408889634f
#define L2E2 2.8853900817779268f

// ---------------------------------------------------------------------------
// Kernel 1: embedding gather + input projection for both directions.
// xproj[((dir*SS + s)*BB + b)*G4 + g] = b_dir[g] + sum_e emb[tok(s,b)][e]*W_ih_dir[e][g]
// grid = SS blocks, block = 320 threads (2 halves of 16 batch x 160 gates)
// ---------------------------------------------------------------------------
__global__ __launch_bounds__(320) void k_embed_proj(
    const int* __restrict__ x, const float* __restrict__ emb,
    const float* __restrict__ Wf, const float* __restrict__ bf,
    const float* __restrict__ Wb, const float* __restrict__ bb,
    float* __restrict__ xproj)
{
    __shared__ float xv[BB * EE];
    __shared__ int toks[BB];
    const int s = blockIdx.x, tid = threadIdx.x;
    if (tid < BB) {
        int b = tid;
        toks[b] = (s == 0) ? PAD1 : (s == SS - 1) ? PAD2 : x[b * TT + (s - 1)];
    }
    __syncthreads();
    for (int i = tid; i < BB * EE; i += 320) {
        int b = i >> 7, e = i & (EE - 1);
        xv[i] = emb[toks[b] * EE + e];
    }
    __syncthreads();

    const int g = tid % 160, half = tid / 160;
    const int dir = (g >= 80) ? 1 : 0;
    const int gg = g - dir * 80;
    const float* W = dir ? Wb : Wf;
    const float bias = dir ? bb[gg] : bf[gg];
    float acc[16];
#pragma unroll
    for (int p = 0; p < 16; ++p) acc[p] = bias;
    const float* xvb = &xv[half * 16 * EE];
    for (int e = 0; e < EE; e += 4) {
        float w0 = W[(e + 0) * G4 + gg];
        float w1 = W[(e + 1) * G4 + gg];
        float w2 = W[(e + 2) * G4 + gg];
        float w3 = W[(e + 3) * G4 + gg];
#pragma unroll
        for (int p = 0; p < 16; ++p) {
            float4 v = *(const float4*)&xvb[p * EE + e];
            acc[p] = fmaf(v.x, w0, acc[p]);
            acc[p] = fmaf(v.y, w1, acc[p]);
            acc[p] = fmaf(v.z, w2, acc[p]);
            acc[p] = fmaf(v.w, w3, acc[p]);
        }
    }
#pragma unroll
    for (int p = 0; p < 16; ++p) {
        int b = half * 16 + p;
        xproj[((dir * SS + s) * BB + b) * G4 + gg] = acc[p];
    }
}

// ---------------------------------------------------------------------------
// Kernel 2: the sequential LSTM recurrence. One wave per (dir, b): 64 blocks
// of 64 threads. Lane = gate: lanes 0..19 = i gates (and o gates as second
// accumulator), 20..39 = f, 40..59 = g(cell). h[q] lives in lane q; broadcast
// via v_readlane. Gate redistribution via ds_bpermute. xproj already has bias.
// ---------------------------------------------------------------------------
__global__ __launch_bounds__(64) void k_lstm(
    const float* __restrict__ Whf, const float* __restrict__ Whb,
    const float* __restrict__ xproj, float* __restrict__ hbuf)
{
    const int id = blockIdx.x;
    const int dir = id >> 5, b = id & 31;
    const int lane = threadIdx.x;
    const float* Wh = dir ? Whb : Whf;

    const int pg = lane;                           // primary gate col (<80, valid for all 64 lanes)
    const int sg = 60 + (lane < QQ ? lane : 0);    // secondary: o-gate col (lanes 0..19 meaningful)

    float wp[QQ], ws[QQ];
#pragma unroll
    for (int q = 0; q < QQ; ++q) {
        wp[q] = Wh[q * G4 + pg];
        ws[q] = Wh[q * G4 + sg];
    }

    const float* xpb = xproj + (size_t)(dir * SS) * BB * G4 + b * G4;
    float* hout = hbuf + (size_t)(dir * SS) * BB * QQ + b * QQ + lane;

    const bool isg = (lane >= 40) && (lane < 60);
    const float scl = isg ? -L2E2 : -L2E;
    const float mula = isg ? 2.0f : 1.0f;
    const float addb = isg ? -1.0f : 0.0f;
    const int addr20 = (lane + 20) * 4;
    const int addr40 = (lane + 40) * 4;

    float h = 0.0f, c = 0.0f;
    int sidx0 = dir ? (SS - 1) : 0;
    float xp_p = xpb[sidx0 * (BB * G4) + pg];
    float xp_s = xpb[sidx0 * (BB * G4) + sg];

    for (int s = 0; s < SS; ++s) {
        const int sn = (s + 1 < SS) ? s + 1 : s;
        const int sidxn = dir ? (SS - 1 - sn) : sn;
        // prefetch next step's input projections
        float np = xpb[sidxn * (BB * G4) + pg];
        float ns = xpb[sidxn * (BB * G4) + sg];

        float accp = xp_p, accs = xp_s;
#pragma unroll
        for (int q = 0; q < QQ; ++q) {
            float hq = __uint_as_float(__builtin_amdgcn_readlane(__float_as_uint(h), q));
            accp = fmaf(hq, wp[q], accp);
            accs = fmaf(hq, ws[q], accs);
        }
        // activation: sigmoid for i/f/o lanes, tanh (=2*sigmoid(2x)-1) for g lanes
        float tp = frcp(1.0f + fexp2(accp * scl));
        float actp = fmaf(mula, tp, addb);
        float acts = frcp(1.0f + fexp2(accs * -L2E));   // sigmoid(o) on lanes 0..19

        // redistribute to unit lanes q' = 0..19
        float sf = __uint_as_float(__builtin_amdgcn_ds_bpermute(addr20, __float_as_uint(actp)));
        float tg = __uint_as_float(__builtin_amdgcn_ds_bpermute(addr40, __float_as_uint(actp)));

        c = fmaf(sf, c, actp * tg);                      // sigma(f)*c + sigma(i)*tanh(g)
        float th = fmaf(2.0f, frcp(1.0f + fexp2(c * -L2E2)), -1.0f);  // tanh(c)
        h = acts * th;

        const int sidx = dir ? (SS - 1 - s) : s;
        if (lane < QQ) hout[(size_t)sidx * BB * QQ] = h;

        xp_p = np; xp_s = ns;
    }
}

// ---------------------------------------------------------------------------
// Kernel 3: band scores + emission assembly.
// One thread per (l, e, b); computes K=50 outputs.
// emission[l,e,b,k]; invalid (start<0) -> NEG.
// __launch_bounds__(256,1): allow ~cat[40]+u[20] to live in VGPRs (R1: the
// compiler capped at 52 VGPRs and spilled -> 100us latency-bound dispatch).
// Uniform control flow (no early return) so W1/W2 loads scalarize to s_load.
// ---------------------------------------------------------------------------
__global__ __launch_bounds__(256, 1) void k_scores(
    const float* __restrict__ hbuf,
    const float* __restrict__ W1, const float* __restrict__ b1,
    const float* __restrict__ W2, const float* __restrict__ b2,
    float* __restrict__ out)
{
    const int idx = blockIdx.x * 256 + threadIdx.x;   // == (l*TT + e)*BB + b
    const int l = idx >> 13;            // / (TT*BB) = 8192
    const int r = idx & 8191;
    const int e = r >> 5;
    const int b = r & 31;
    float* op = out + (size_t)idx * KK;

    const int start = e - (LL - 1) + l;
    const bool valid = (start >= 0);
    const int st = valid ? start : 0;

    // fwd[b][t] = hf[t+1][b]; bwd[b][t] = hb[t][b]
    const float4* hfA = (const float4*)(hbuf + ((size_t)(e + 2) * BB + b) * QQ);      // fwd[b][e+1]
    const float4* hfB = (const float4*)(hbuf + ((size_t)(st + 1) * BB + b) * QQ);     // fwd[b][start]
    const float4* hbA = (const float4*)(hbuf + ((size_t)(SS + st) * BB + b) * QQ);    // bwd[b][start]
    const float4* hbB = (const float4*)(hbuf + ((size_t)(SS + e + 1) * BB + b) * QQ); // bwd[b][e+1]

    float cat[2 * QQ];
#pragma unroll
    for (int j = 0; j < 5; ++j) {
        float4 a = hfA[j], d = hfB[j];
        cat[4 * j + 0] = a.x - d.x; cat[4 * j + 1] = a.y - d.y;
        cat[4 * j + 2] = a.z - d.z; cat[4 * j + 3] = a.w - d.w;
        float4 p = hbA[j], q = hbB[j];
        cat[QQ + 4 * j + 0] = p.x - q.x; cat[QQ + 4 * j + 1] = p.y - q.y;
        cat[QQ + 4 * j + 2] = p.z - q.z; cat[QQ + 4 * j + 3] = p.w - q.w;
    }

    float u[QQ];
#pragma unroll
    for (int j = 0; j < QQ; ++j) {
        float a = b1[j];
#pragma unroll
        for (int d = 0; d < 2 * QQ; ++d) a = fmaf(cat[d], W1[d * QQ + j], a);
        u[j] = fmaf(2.0f, frcp(1.0f + fexp2(a * -L2E2)), -1.0f);   // tanh
    }
#pragma unroll
    for (int k = 0; k < KK; ++k) {
        float a = b2[k];
#pragma unroll
        for (int j = 0; j < QQ; ++j) a = fmaf(u[j], W2[j * KK + k], a);
        op[k] = valid ? a : NEGV;      // branchless: v_cndmask, keeps CF uniform
    }
}

extern "C" void kernel_launch(void* const* d_in, const int* in_sizes, int n_in,
                              void* d_out, int out_size, void* d_ws, size_t ws_size,
                              hipStream_t stream)
{
    const int*   x    = (const int*)d_in[0];
    const float* emb  = (const float*)d_in[1];
    const float* Wihf = (const float*)d_in[2];
    const float* Whhf = (const float*)d_in[3];
    const float* bf   = (const float*)d_in[4];
    const float* Wihb = (const float*)d_in[5];
    const float* Whhb = (const float*)d_in[6];
    const float* bb   = (const float*)d_in[7];
    const float* W1   = (const float*)d_in[8];
    const float* b1   = (const float*)d_in[9];
    const float* W2   = (const float*)d_in[10];
    const float* b2   = (const float*)d_in[11];
    float* out = (float*)d_out;

    float* xproj = (float*)d_ws;                         // 2*258*32*80 floats
    float* hbuf  = xproj + (size_t)2 * SS * BB * G4;     // 2*258*32*20 floats

    k_embed_proj<<<SS, 320, 0, stream>>>(x, emb, Wihf, bf, Wihb, bb, xproj);
    k_lstm<<<64, 64, 0, stream>>>(Whhf, Whhb, xproj, hbuf);
    k_scores<<<(LL * TT * BB) / 256, 256, 0, stream>>>(hbuf, W1, b1, W2, b2, out);
}

// Round 3
// 228.465 us; speedup vs baseline: 1.0390x; 1.0213x over previous
//
#include <hip/hip_runtime.h>

#define BB 32
#define TT 256
#define SS 258
#define EE 128
#define QQ 20
#define G4 80
#define KK 50
#define LL 8
#define PAD1 2
#define PAD2 3
#define NEGV -1e30f

typedef float v2f __attribute__((ext_vector_type(2)));

__device__ __forceinline__ float fexp2(float x) {
#if __has_builtin(__builtin_amdgcn_exp2f)
    return __builtin_amdgcn_exp2f(x);
#else
    return exp2f(x);
#endif
}
__device__ __forceinline__ float frcp(float x) {
#if __has_builtin(__builtin_amdgcn_rcpf)
    return __builtin_amdgcn_rcpf(x);
#else
    return 1.0f / x;
#endif
}

// log2(e), 2*log2(e)
#define L2E  1.4426950408889634f
#define L2E2 2.8853900817779268f

// ---------------------------------------------------------------------------
// Kernel 1: embedding gather + input projection for both directions.
// (unchanged this round — isolating the k_lstm experiment)
// ---------------------------------------------------------------------------
__global__ __launch_bounds__(320) void k_embed_proj(
    const int* __restrict__ x, const float* __restrict__ emb,
    const float* __restrict__ Wf, const float* __restrict__ bf,
    const float* __restrict__ Wb, const float* __restrict__ bb,
    float* __restrict__ xproj)
{
    __shared__ float xv[BB * EE];
    __shared__ int toks[BB];
    const int s = blockIdx.x, tid = threadIdx.x;
    if (tid < BB) {
        int b = tid;
        toks[b] = (s == 0) ? PAD1 : (s == SS - 1) ? PAD2 : x[b * TT + (s - 1)];
    }
    __syncthreads();
    for (int i = tid; i < BB * EE; i += 320) {
        int b = i >> 7, e = i & (EE - 1);
        xv[i] = emb[toks[b] * EE + e];
    }
    __syncthreads();

    const int g = tid % 160, half = tid / 160;
    const int dir = (g >= 80) ? 1 : 0;
    const int gg = g - dir * 80;
    const float* W = dir ? Wb : Wf;
    const float bias = dir ? bb[gg] : bf[gg];
    float acc[16];
#pragma unroll
    for (int p = 0; p < 16; ++p) acc[p] = bias;
    const float* xvb = &xv[half * 16 * EE];
    for (int e = 0; e < EE; e += 4) {
        float w0 = W[(e + 0) * G4 + gg];
        float w1 = W[(e + 1) * G4 + gg];
        float w2 = W[(e + 2) * G4 + gg];
        float w3 = W[(e + 3) * G4 + gg];
#pragma unroll
        for (int p = 0; p < 16; ++p) {
            float4 v = *(const float4*)&xvb[p * EE + e];
            acc[p] = fmaf(v.x, w0, acc[p]);
            acc[p] = fmaf(v.y, w1, acc[p]);
            acc[p] = fmaf(v.z, w2, acc[p]);
            acc[p] = fmaf(v.w, w3, acc[p]);
        }
    }
#pragma unroll
    for (int p = 0; p < 16; ++p) {
        int b = half * 16 + p;
        xproj[((dir * SS + s) * BB + b) * G4 + gg] = acc[p];
    }
}

// ---------------------------------------------------------------------------
// Kernel 2: sequential LSTM recurrence. One wave per (dir,b).
// R2 fix: VGPR_Count was 32 -> recurrent weights spilled to scratch (89us).
//  - __launch_bounds__(64,1): lift VGPR cap so weights stay resident.
//  - h broadcast via LDS (lanes 0..19 ds_write, all lanes 5x ds_read_b128
//    uniform/broadcast) instead of 20 serial v_readlane.
//  - matvec as v_pk_fma_f32 over packed h pairs: 20 pk-FMAs, 2 chains each.
// Lane = gate col: 0..19=i, 20..39=f, 40..59=g, (60..63 unused dup);
// lanes 0..19 also accumulate the o-gate (cols 60..79) in a second acc.
// ---------------------------------------------------------------------------
__global__ __launch_bounds__(64, 1) void k_lstm(
    const float* __restrict__ Whf, const float* __restrict__ Whb,
    const float* __restrict__ xproj, float* __restrict__ hbuf)
{
    __shared__ float hsh[32];   // h state, q=0..19 (padded)
    const int id = blockIdx.x;
    const int dir = id >> 5, b = id & 31;
    const int lane = threadIdx.x;
    const float* Wh = dir ? Whb : Whf;

    const int pg = lane;                           // primary gate col (<80)
    const int sg = 60 + (lane < QQ ? lane : 0);    // o-gate col (lanes 0..19)

    // packed recurrent weights: pair over contraction index q
    v2f wpp[10], wsp[10];
#pragma unroll
    for (int j = 0; j < 10; ++j) {
        wpp[j] = v2f{Wh[(2 * j) * G4 + pg], Wh[(2 * j + 1) * G4 + pg]};
        wsp[j] = v2f{Wh[(2 * j) * G4 + sg], Wh[(2 * j + 1) * G4 + sg]};
    }

    const float* xpb = xproj + (size_t)(dir * SS) * BB * G4 + b * G4;
    float* hout = hbuf + (size_t)(dir * SS) * BB * QQ + b * QQ + lane;

    const bool isg = (lane >= 40) && (lane < 60);
    const float scl = isg ? -L2E2 : -L2E;
    const float mula = isg ? 2.0f : 1.0f;
    const float addb = isg ? -1.0f : 0.0f;
    const int addr20 = (lane + 20) * 4;
    const int addr40 = (lane + 40) * 4;

    if (lane < 32) hsh[lane] = 0.0f;
    __syncthreads();

    float c = 0.0f;
    int sidx0 = dir ? (SS - 1) : 0;
    float xp_p = xpb[sidx0 * (BB * G4) + pg];
    float xp_s = xpb[sidx0 * (BB * G4) + sg];

    const float4* hs4 = (const float4*)hsh;

    for (int s = 0; s < SS; ++s) {
        const int sn = (s + 1 < SS) ? s + 1 : s;
        const int sidxn = dir ? (SS - 1 - sn) : sn;
        float np = xpb[sidxn * (BB * G4) + pg];
        float ns = xpb[sidxn * (BB * G4) + sg];

        // broadcast h from LDS, packed in pairs
        float4 h0 = hs4[0], h1 = hs4[1], h2 = hs4[2], h3 = hs4[3], h4v = hs4[4];
        v2f hp[10] = {v2f{h0.x, h0.y}, v2f{h0.z, h0.w},
                      v2f{h1.x, h1.y}, v2f{h1.z, h1.w},
                      v2f{h2.x, h2.y}, v2f{h2.z, h2.w},
                      v2f{h3.x, h3.y}, v2f{h3.z, h3.w},
                      v2f{h4v.x, h4v.y}, v2f{h4v.z, h4v.w}};

        v2f a0 = v2f{0.f, 0.f}, a1 = v2f{0.f, 0.f};
        v2f s0 = v2f{0.f, 0.f}, s1 = v2f{0.f, 0.f};
#pragma unroll
        for (int j = 0; j < 10; j += 2) {
            a0 = __builtin_elementwise_fma(hp[j], wpp[j], a0);
            s0 = __builtin_elementwise_fma(hp[j], wsp[j], s0);
            a1 = __builtin_elementwise_fma(hp[j + 1], wpp[j + 1], a1);
            s1 = __builtin_elementwise_fma(hp[j + 1], wsp[j + 1], s1);
        }
        float accp = xp_p + ((a0.x + a0.y) + (a1.x + a1.y));
        float accs = xp_s + ((s0.x + s0.y) + (s1.x + s1.y));

        // activations: sigmoid for i/f/o lanes, tanh for g lanes
        float tp = frcp(1.0f + fexp2(accp * scl));
        float actp = fmaf(mula, tp, addb);
        float acts = frcp(1.0f + fexp2(accs * -L2E));   // sigmoid(o), lanes 0..19

        // redistribute f,g to unit lanes 0..19
        float sf = __uint_as_float(__builtin_amdgcn_ds_bpermute(addr20, __float_as_uint(actp)));
        float tg = __uint_as_float(__builtin_amdgcn_ds_bpermute(addr40, __float_as_uint(actp)));

        c = fmaf(sf, c, actp * tg);                      // f*c + i*tanh(g)
        float th = fmaf(2.0f, frcp(1.0f + fexp2(c * -L2E2)), -1.0f);  // tanh(c)
        float h = acts * th;

        if (lane < QQ) hsh[lane] = h;                    // publish state for next step

        const int sidx = dir ? (SS - 1 - s) : s;
        if (lane < QQ) hout[(size_t)sidx * BB * QQ] = h;

        xp_p = np; xp_s = ns;
    }
}

// ---------------------------------------------------------------------------
// Kernel 3: band scores + emission assembly. (unchanged from R1 fix)
// ---------------------------------------------------------------------------
__global__ __launch_bounds__(256, 1) void k_scores(
    const float* __restrict__ hbuf,
    const float* __restrict__ W1, const float* __restrict__ b1,
    const float* __restrict__ W2, const float* __restrict__ b2,
    float* __restrict__ out)
{
    const int idx = blockIdx.x * 256 + threadIdx.x;   // == (l*TT + e)*BB + b
    const int l = idx >> 13;            // / (TT*BB) = 8192
    const int r = idx & 8191;
    const int e = r >> 5;
    const int b = r & 31;
    float* op = out + (size_t)idx * KK;

    const int start = e - (LL - 1) + l;
    const bool valid = (start >= 0);
    const int st = valid ? start : 0;

    // fwd[b][t] = hf[t+1][b]; bwd[b][t] = hb[t][b]
    const float4* hfA = (const float4*)(hbuf + ((size_t)(e + 2) * BB + b) * QQ);      // fwd[b][e+1]
    const float4* hfB = (const float4*)(hbuf + ((size_t)(st + 1) * BB + b) * QQ);     // fwd[b][start]
    const float4* hbA = (const float4*)(hbuf + ((size_t)(SS + st) * BB + b) * QQ);    // bwd[b][start]
    const float4* hbB = (const float4*)(hbuf + ((size_t)(SS + e + 1) * BB + b) * QQ); // bwd[b][e+1]

    float cat[2 * QQ];
#pragma unroll
    for (int j = 0; j < 5; ++j) {
        float4 a = hfA[j], d = hfB[j];
        cat[4 * j + 0] = a.x - d.x; cat[4 * j + 1] = a.y - d.y;
        cat[4 * j + 2] = a.z - d.z; cat[4 * j + 3] = a.w - d.w;
        float4 p = hbA[j], q = hbB[j];
        cat[QQ + 4 * j + 0] = p.x - q.x; cat[QQ + 4 * j + 1] = p.y - q.y;
        cat[QQ + 4 * j + 2] = p.z - q.z; cat[QQ + 4 * j + 3] = p.w - q.w;
    }

    float u[QQ];
#pragma unroll
    for (int j = 0; j < QQ; ++j) {
        float a = b1[j];
#pragma unroll
        for (int d = 0; d < 2 * QQ; ++d) a = fmaf(cat[d], W1[d * QQ + j], a);
        u[j] = fmaf(2.0f, frcp(1.0f + fexp2(a * -L2E2)), -1.0f);   // tanh
    }
#pragma unroll
    for (int k = 0; k < KK; ++k) {
        float a = b2[k];
#pragma unroll
        for (int j = 0; j < QQ; ++j) a = fmaf(u[j], W2[j * KK + k], a);
        op[k] = valid ? a : NEGV;      // branchless select, uniform CF
    }
}

extern "C" void kernel_launch(void* const* d_in, const int* in_sizes, int n_in,
                              void* d_out, int out_size, void* d_ws, size_t ws_size,
                              hipStream_t stream)
{
    const int*   x    = (const int*)d_in[0];
    const float* emb  = (const float*)d_in[1];
    const float* Wihf = (const float*)d_in[2];
    const float* Whhf = (const float*)d_in[3];
    const float* bf   = (const float*)d_in[4];
    const float* Wihb = (const float*)d_in[5];
    const float* Whhb = (const float*)d_in[6];
    const float* bb   = (const float*)d_in[7];
    const float* W1   = (const float*)d_in[8];
    const float* b1   = (const float*)d_in[9];
    const float* W2   = (const float*)d_in[10];
    const float* b2   = (const float*)d_in[11];
    float* out = (float*)d_out;

    float* xproj = (float*)d_ws;                         // 2*258*32*80 floats
    float* hbuf  = xproj + (size_t)2 * SS * BB * G4;     // 2*258*32*20 floats

    k_embed_proj<<<SS, 320, 0, stream>>>(x, emb, Wihf, bf, Wihb, bb, xproj);
    k_lstm<<<64, 64, 0, stream>>>(Whhf, Whhb, xproj, hbuf);
    k_scores<<<(LL * TT * BB) / 256, 256, 0, stream>>>(hbuf, W1, b1, W2, b2, out);
}